// Round 18
// baseline (166.793 us; speedup 1.0000x reference)
//
#include <hip/hip_runtime.h>

#define NN 3000
#define NB 8
#define TP 12
#define DMAX 128
#define F1T 480    // block-1 packed features: h(8*24) + d(8*12) + w(8*24)
#define F2T 768    // block-2 packed features: 3 * 8 * 32

struct BrW {
    const float *W1[3]; const float *b1[3]; const float *c1w[3]; const float *c1b[3];
    const float *W2[3]; const float *b2[3]; const float *c2w[3]; const float *c2b[3];
    const float *Fb[3];
};

// ---------------- merged: Laplacian build (raw vals) + pack Xh|Xd|Xw -> xcat ----------------
__global__ void build_pack_kernel(const float* __restrict__ A, int* __restrict__ colp,
                                  float* __restrict__ valp, int* __restrict__ cnt,
                                  float* __restrict__ dinv,
                                  const float* __restrict__ Xh, const float* __restrict__ Xd,
                                  const float* __restrict__ Xw, float* __restrict__ xcat) {
    int bid = blockIdx.x;
    if (bid < 750) {
        int wid = threadIdx.x >> 6;
        int lane = threadIdx.x & 63;
        int n = bid * 4 + wid;            // 0..2999
        const float4* row4 = reinterpret_cast<const float4*>(A + (size_t)n * NN);
        int base = 0;
        float s = 0.f;
        for (int start = 0; start < 750; start += 64) {   // NN/4 = 750 float4s
            int m4 = start + lane;
            float4 v = make_float4(0.f, 0.f, 0.f, 0.f);
            if (m4 < 750) v = row4[m4];
            float vals[4] = {v.x, v.y, v.z, v.w};
            int mbase = m4 * 4;
            #pragma unroll
            for (int u = 0; u < 4; ++u) {
                int m = mbase + u;
                float a = (m4 < 750 && m != n) ? vals[u] : 0.f;
                bool nz = (a != 0.f);
                s += a;
                unsigned long long mask = __ballot(nz);
                int off = __popcll(mask & ((1ull << lane) - 1ull));
                if (nz) {
                    int idx = base + off;
                    if (idx < DMAX) { colp[n * DMAX + idx] = m; valp[n * DMAX + idx] = a; }
                }
                base += __popcll(mask);
            }
        }
        for (int o = 32; o > 0; o >>= 1) s += __shfl_down(s, o);
        if (lane == 0) {
            cnt[n] = (base < DMAX) ? base : DMAX;
            dinv[n] = (s > 0.f) ? 1.0f / sqrtf(s) : 0.f;
        }
    } else {
        int idx = (bid - 750) * 256 + threadIdx.x;
        if (idx >= NN * F1T) return;
        int n = idx / F1T, r = idx % F1T;
        const float* src; int b, t, T;
        if (r < 192)      { src = Xh; T = 24; int rr = r;       b = rr / 24; t = rr % 24; }
        else if (r < 288) { src = Xd; T = 12; int rr = r - 192; b = rr / 12; t = rr % 12; }
        else              { src = Xw; T = 24; int rr = r - 288; b = rr / 24; t = rr % 24; }
        xcat[idx] = src[((size_t)b * NN + n) * T + t];
    }
}

// ---------------- SpMM, scalar gathers, 32-deep ILP, XCD-swizzled slices ----------------
// Edge scaling -dinv[n]*a*dinv[m] folded into LDS staging (dinv is L1-hot, 12 KB).
// EPI 0: y = Lx ; EPI 1: y = 2*Lx - aux ; EPI 2: y = aux + 2*Lx
template <int F, int SLICE, int EPI>
__global__ void spmm_kernel(const int* __restrict__ colp, const float* __restrict__ valp,
                            const int* __restrict__ cnt, const float* __restrict__ dinv,
                            const float* __restrict__ x, const float* __restrict__ aux,
                            float* __restrict__ y) {
    int nwg = gridDim.x;
    int q = nwg >> 3;
    int bid = blockIdx.x;
    int w = (bid & 7) * q + (bid >> 3);   // XCD-contiguous chunks (nwg % 8 == 0)
    int slice = w / NN;
    int n = w - slice * NN;
    int f = slice * SLICE + threadIdx.x;

    __shared__ int   scol[DMAX];
    __shared__ float sval[DMAX];
    int c = cnt[n];
    float dn = -dinv[n];
    if (threadIdx.x < DMAX) {
        int j = threadIdx.x;
        bool ok = j < c;
        int m = ok ? colp[n * DMAX + j] : 0;
        scol[j] = ok ? m * F : 0;
        sval[j] = ok ? dn * valp[n * DMAX + j] * dinv[m] : 0.f;
    }
    __syncthreads();
    int c32 = (c + 31) & ~31;
    float a0 = 0.f, a1 = 0.f, a2 = 0.f, a3 = 0.f;
    float a4 = 0.f, a5 = 0.f, a6 = 0.f, a7 = 0.f;
    if (f < F) {
        for (int i = 0; i < c32; i += 32) {
            float g[32], w32[32];
            #pragma unroll
            for (int u = 0; u < 32; ++u) {
                int cc = scol[i + u];
                w32[u] = sval[i + u];
                g[u] = x[cc + f];
            }
            #pragma unroll
            for (int u = 0; u < 32; u += 8) {
                a0 += w32[u + 0] * g[u + 0]; a1 += w32[u + 1] * g[u + 1];
                a2 += w32[u + 2] * g[u + 2]; a3 += w32[u + 3] * g[u + 3];
                a4 += w32[u + 4] * g[u + 4]; a5 += w32[u + 5] * g[u + 5];
                a6 += w32[u + 6] * g[u + 6]; a7 += w32[u + 7] * g[u + 7];
            }
        }
    }
    if (f >= F) return;
    float acc = ((a0 + a1) + (a2 + a3)) + ((a4 + a5) + (a6 + a7));
    size_t o = (size_t)n * F + f;
    if (EPI == 1) acc = 2.f * acc - aux[o];
    else if (EPI == 2) acc = aux[o] + 2.f * acc;
    y[o] = acc;
}

// ---------------- fused block-1 combine (GEMM1+tconv) + y-GEMM (GEMM2) ----------------
// Round-12 structure (256 thr, 3 rows x 8/12 cols) + float4 z-reads over k.
#define SZ_LDA 68
template <int T, int OFF>
__device__ __forceinline__ void fused1_body(
        int tile, int br, const float* __restrict__ xcat, const float* __restrict__ t1cat,
        const float* __restrict__ t2cat, float* __restrict__ y1cat,
        float* __restrict__ y2cat, float* __restrict__ c0cat, const BrW& P, float* smem) {
    constexpr int K = 3 * T;
    constexpr int LDA = K + 4;           // multiple of 4 (float4 z-reads), banks OK
    int tid = threadIdx.x;
    float* sW1 = smem;                   // K*64
    float* sX  = smem + K * 64;          // 96*LDA
    const float* W1 = P.W1[br];
    for (int i = tid; i < K * 64; i += 256) sW1[i] = W1[i];
    int n0 = tile * 12;
    #pragma unroll
    for (int s = 0; s < 3; ++s) {
        const float* src = (s == 0) ? xcat : (s == 1) ? t1cat : t2cat;
        for (int i = tid; i < 96 * T; i += 256) {
            int n_l = i / (8 * T), rem = i % (8 * T);
            int b = rem / T, ii = rem % T;
            sX[(n_l * 8 + b) * LDA + s * T + ii] =
                src[(size_t)(n0 + n_l) * F1T + OFF + b * T + ii];
        }
    }
    __syncthreads();

    int rq = tid >> 3;       // 0..31 -> rows rq*3..rq*3+2
    int g  = tid & 7;        // cols g*8..g*8+7
    float acc[3][8];
    #pragma unroll
    for (int r = 0; r < 3; ++r)
        #pragma unroll
        for (int j = 0; j < 8; ++j) acc[r][j] = 0.f;

    for (int k4 = 0; k4 < K; k4 += 4) {
        float4 zq0 = *reinterpret_cast<const float4*>(sX + (rq * 3 + 0) * LDA + k4);
        float4 zq1 = *reinterpret_cast<const float4*>(sX + (rq * 3 + 1) * LDA + k4);
        float4 zq2 = *reinterpret_cast<const float4*>(sX + (rq * 3 + 2) * LDA + k4);
        #pragma unroll
        for (int kk = 0; kk < 4; ++kk) {
            const float4* wr = reinterpret_cast<const float4*>(sW1 + (k4 + kk) * 64 + g * 8);
            float4 wa = wr[0], wb = wr[1];
            float zv0 = (kk == 0) ? zq0.x : (kk == 1) ? zq0.y : (kk == 2) ? zq0.z : zq0.w;
            float zv1 = (kk == 0) ? zq1.x : (kk == 1) ? zq1.y : (kk == 2) ? zq1.z : zq1.w;
            float zv2 = (kk == 0) ? zq2.x : (kk == 1) ? zq2.y : (kk == 2) ? zq2.z : zq2.w;
            acc[0][0] += zv0 * wa.x; acc[0][1] += zv0 * wa.y;
            acc[0][2] += zv0 * wa.z; acc[0][3] += zv0 * wa.w;
            acc[0][4] += zv0 * wb.x; acc[0][5] += zv0 * wb.y;
            acc[0][6] += zv0 * wb.z; acc[0][7] += zv0 * wb.w;
            acc[1][0] += zv1 * wa.x; acc[1][1] += zv1 * wa.y;
            acc[1][2] += zv1 * wa.z; acc[1][3] += zv1 * wa.w;
            acc[1][4] += zv1 * wb.x; acc[1][5] += zv1 * wb.y;
            acc[1][6] += zv1 * wb.z; acc[1][7] += zv1 * wb.w;
            acc[2][0] += zv2 * wa.x; acc[2][1] += zv2 * wa.y;
            acc[2][2] += zv2 * wa.z; acc[2][3] += zv2 * wa.w;
            acc[2][4] += zv2 * wb.x; acc[2][5] += zv2 * wb.y;
            acc[2][6] += zv2 * wb.z; acc[2][7] += zv2 * wb.w;
        }
    }

    float bgv[8];
    #pragma unroll
    for (int j = 0; j < 8; ++j) bgv[j] = P.b1[br][g * 8 + j];
    float w0 = P.c1w[br][0], w1 = P.c1w[br][1], w2 = P.c1w[br][2], bb = P.c1b[br][0];

    float o[3][8];
    #pragma unroll
    for (int r = 0; r < 3; ++r) {
        float z[8];
        #pragma unroll
        for (int j = 0; j < 8; ++j) z[j] = fmaxf(acc[r][j] + bgv[j], 0.f);
        float zl = __shfl_up(z[7], 1);
        float zr = __shfl_down(z[0], 1);
        #pragma unroll
        for (int j = 0; j < 8; ++j) {
            float left  = (j > 0) ? z[j - 1] : ((g > 0) ? zl : 0.f);
            float right = (j < 7) ? z[j + 1] : ((g < 7) ? zr : 0.f);
            o[r][j] = fmaxf(w0 * left + w1 * z[j] + w2 * right + bb, 0.f);
        }
    }
    __syncthreads();   // all phase-1 LDS reads done; regions reused

    float* sZ  = smem;                 // 96 * SZ_LDA
    float* sW2 = smem + 96 * SZ_LDA;   // 64*96 interleaved
    #pragma unroll
    for (int r = 0; r < 3; ++r) {
        float* dst = sZ + (rq * 3 + r) * SZ_LDA + g * 8;
        reinterpret_cast<float4*>(dst)[0] = make_float4(o[r][0], o[r][1], o[r][2], o[r][3]);
        reinterpret_cast<float4*>(dst)[1] = make_float4(o[r][4], o[r][5], o[r][6], o[r][7]);
    }
    const float* W2 = P.W2[br];        // (3, 64, 32)
    for (int i = tid; i < 6144; i += 256) {
        int k = i / 96, cc = i % 96;
        int j = cc / 3, m = cc % 3;
        sW2[i] = W2[m * 2048 + k * 32 + j];
    }
    __syncthreads();

    float acc2[3][12];
    #pragma unroll
    for (int r = 0; r < 3; ++r)
        #pragma unroll
        for (int j = 0; j < 12; ++j) acc2[r][j] = 0.f;

    for (int k4 = 0; k4 < 64; k4 += 4) {
        float4 zq0 = *reinterpret_cast<const float4*>(sZ + (rq * 3 + 0) * SZ_LDA + k4);
        float4 zq1 = *reinterpret_cast<const float4*>(sZ + (rq * 3 + 1) * SZ_LDA + k4);
        float4 zq2 = *reinterpret_cast<const float4*>(sZ + (rq * 3 + 2) * SZ_LDA + k4);
        #pragma unroll
        for (int kk = 0; kk < 4; ++kk) {
            const float4* wr = reinterpret_cast<const float4*>(sW2 + (k4 + kk) * 96 + g * 12);
            float4 wa = wr[0], wb = wr[1], wc = wr[2];
            float zv0 = (kk == 0) ? zq0.x : (kk == 1) ? zq0.y : (kk == 2) ? zq0.z : zq0.w;
            float zv1 = (kk == 0) ? zq1.x : (kk == 1) ? zq1.y : (kk == 2) ? zq1.z : zq1.w;
            float zv2 = (kk == 0) ? zq2.x : (kk == 1) ? zq2.y : (kk == 2) ? zq2.z : zq2.w;
            acc2[0][0] += zv0 * wa.x;  acc2[0][1] += zv0 * wa.y;
            acc2[0][2] += zv0 * wa.z;  acc2[0][3] += zv0 * wa.w;
            acc2[0][4] += zv0 * wb.x;  acc2[0][5] += zv0 * wb.y;
            acc2[0][6] += zv0 * wb.z;  acc2[0][7] += zv0 * wb.w;
            acc2[0][8] += zv0 * wc.x;  acc2[0][9] += zv0 * wc.y;
            acc2[0][10] += zv0 * wc.z; acc2[0][11] += zv0 * wc.w;
            acc2[1][0] += zv1 * wa.x;  acc2[1][1] += zv1 * wa.y;
            acc2[1][2] += zv1 * wa.z;  acc2[1][3] += zv1 * wa.w;
            acc2[1][4] += zv1 * wb.x;  acc2[1][5] += zv1 * wb.y;
            acc2[1][6] += zv1 * wb.z;  acc2[1][7] += zv1 * wb.w;
            acc2[1][8] += zv1 * wc.x;  acc2[1][9] += zv1 * wc.y;
            acc2[1][10] += zv1 * wc.z; acc2[1][11] += zv1 * wc.w;
            acc2[2][0] += zv2 * wa.x;  acc2[2][1] += zv2 * wa.y;
            acc2[2][2] += zv2 * wa.z;  acc2[2][3] += zv2 * wa.w;
            acc2[2][4] += zv2 * wb.x;  acc2[2][5] += zv2 * wb.y;
            acc2[2][6] += zv2 * wb.z;  acc2[2][7] += zv2 * wb.w;
            acc2[2][8] += zv2 * wc.x;  acc2[2][9] += zv2 * wc.y;
            acc2[2][10] += zv2 * wc.z; acc2[2][11] += zv2 * wc.w;
        }
    }

    const float* b2 = P.b2[br];
    #pragma unroll
    for (int r = 0; r < 3; ++r) {
        int unit = tile * 96 + rq * 3 + r;
        int n = unit >> 3, b = unit & 7;
        size_t obase = (size_t)n * F2T + br * 256 + b * 32;
        #pragma unroll
        for (int jj = 0; jj < 4; ++jj) {
            int j = g * 4 + jj;
            float a0 = acc2[r][jj * 3 + 0], a1 = acc2[r][jj * 3 + 1], a2 = acc2[r][jj * 3 + 2];
            y1cat[obase + j] = a1;
            y2cat[obase + j] = a2;
            c0cat[obase + j] = a0 - a2 + b2[j];
        }
    }
}

__global__ void __launch_bounds__(256, 3)
fused1_kernel(const float* __restrict__ xcat, const float* __restrict__ t1cat,
              const float* __restrict__ t2cat, float* __restrict__ y1cat,
              float* __restrict__ y2cat, float* __restrict__ c0cat, BrW P) {
    __shared__ float smem[12672];   // 50.7 KB union: max(K*64+96*(K+4), 96*68+6144)
    int b = blockIdx.x;
    if (b < 250)      fused1_body<24, 0>(b, 0, xcat, t1cat, t2cat, y1cat, y2cat, c0cat, P, smem);
    else if (b < 500) fused1_body<12, 192>(b - 250, 1, xcat, t1cat, t2cat, y1cat, y2cat, c0cat, P, smem);
    else              fused1_body<24, 288>(b - 500, 2, xcat, t1cat, t2cat, y1cat, y2cat, c0cat, P, smem);
}

// ---------------- block-2 combine + final linear + fusion, per node ----------------
__global__ void combine2_final_kernel(const float* __restrict__ c0cat,
                                      const float* __restrict__ vcat,
                                      const float* __restrict__ WD, const float* __restrict__ bD,
                                      float* __restrict__ out, BrW P) {
    int n = blockIdx.x;
    __shared__ float z2[3][NB][32];
    int unit = threadIdx.x >> 5;      // 0..23
    int co = threadIdx.x & 31;
    int br = unit >> 3, b = unit & 7;
    size_t o = (size_t)n * F2T + br * 256 + b * 32 + co;
    float a = fmaxf(c0cat[o] + vcat[o], 0.f);
    float left  = __shfl_up(a, 1);
    float right = __shfl_down(a, 1);
    if (co == 0) left = 0.f;
    if (co == 31) right = 0.f;
    float w0 = P.c2w[br][0], w1 = P.c2w[br][1], w2 = P.c2w[br][2], bb = P.c2b[br][0];
    z2[br][b][co] = fmaxf(w0 * left + w1 * a + w2 * right + bb, 0.f);
    __syncthreads();
    if (threadIdx.x < NB * TP) {
        int b2 = threadIdx.x / TP, tp = threadIdx.x % TP;
        float y = 0.f;
        for (int brr = 0; brr < 3; ++brr) {
            float s = bD[tp];
            const float* zz = z2[brr][b2];
            for (int c = 0; c < 32; ++c) s += zz[c] * WD[c * TP + tp];
            y += fmaxf(s, 0.f) * P.Fb[brr][tp];
        }
        out[((size_t)b2 * NN + n) * TP + tp] = y;
    }
}

// ---------------- launcher ----------------

static inline size_t align256(size_t x) { return (x + 255) & ~(size_t)255; }

extern "C" void kernel_launch(void* const* d_in, const int* in_sizes, int n_in,
                              void* d_out, int out_size, void* d_ws, size_t ws_size,
                              hipStream_t stream) {
    const float* Xh = (const float*)d_in[0];
    const float* Xd = (const float*)d_in[1];
    const float* Xw = (const float*)d_in[2];
    const float* A  = (const float*)d_in[3];
    const float* WD = (const float*)d_in[28];
    const float* bD = (const float*)d_in[29];

    BrW P;
    for (int br = 0; br < 3; ++br) {
        int base = 4 + br * 8;
        P.W1[br]  = (const float*)d_in[base + 0];
        P.b1[br]  = (const float*)d_in[base + 1];
        P.c1w[br] = (const float*)d_in[base + 2];
        P.c1b[br] = (const float*)d_in[base + 3];
        P.W2[br]  = (const float*)d_in[base + 4];
        P.b2[br]  = (const float*)d_in[base + 5];
        P.c2w[br] = (const float*)d_in[base + 6];
        P.c2b[br] = (const float*)d_in[base + 7];
        P.Fb[br]  = (const float*)d_in[30 + br];
    }

    char* p = (char*)d_ws;
    int*   colp  = (int*)p;   p += align256((size_t)NN * DMAX * 4);
    float* valp  = (float*)p; p += align256((size_t)NN * DMAX * 4);
    int*   cnt   = (int*)p;   p += align256(NN * 4);
    float* dinv  = (float*)p; p += align256(NN * 4);
    float* xcat  = (float*)p; p += align256((size_t)NN * F1T * 4);
    float* t1cat = (float*)p; p += align256((size_t)NN * F1T * 4);
    float* t2cat = (float*)p; p += align256((size_t)NN * F1T * 4);
    float* y1cat = (float*)p; p += align256((size_t)NN * F2T * 4);
    float* y2cat = (float*)p; p += align256((size_t)NN * F2T * 4);
    float* c0cat = (float*)p; p += align256((size_t)NN * F2T * 4);
    float* scat  = (float*)p; p += align256((size_t)NN * F2T * 4);
    float* vcat  = (float*)p; p += align256((size_t)NN * F2T * 4);

    // build (750 blocks, 4 rows each) + pack (5625 blocks), overlapped in one launch
    build_pack_kernel<<<750 + 5625, 256, 0, stream>>>(A, colp, valp, cnt, dinv,
                                                      Xh, Xd, Xw, xcat);

    // Block 1 (packed, F=480): t1 = L x ; t2 = 2 L t1 - x
    spmm_kernel<F1T, 256, 0><<<6000, 256, 0, stream>>>(colp, valp, cnt, dinv, xcat, nullptr, t1cat);
    spmm_kernel<F1T, 256, 1><<<6000, 256, 0, stream>>>(colp, valp, cnt, dinv, t1cat, xcat, t2cat);

    // Fused: combine1 (cheb+bias+relu+tconv+relu) + W-first y-GEMM
    fused1_kernel<<<750, 256, 0, stream>>>(xcat, t1cat, t2cat, y1cat, y2cat, c0cat, P);

    // Block 2: s = y1 + 2 L y2 ; v = L s ; then combine2 + final + fusion
    spmm_kernel<F2T, 256, 2><<<9000, 256, 0, stream>>>(colp, valp, cnt, dinv, y2cat, y1cat, scat);
    spmm_kernel<F2T, 256, 0><<<9000, 256, 0, stream>>>(colp, valp, cnt, dinv, scat, nullptr, vcat);

    combine2_final_kernel<<<NN, 768, 0, stream>>>(c0cat, vcat, WD, bD, (float*)d_out, P);
}

// Round 19
// 161.979 us; speedup vs baseline: 1.0297x; 1.0297x over previous
//
#include <hip/hip_runtime.h>

#define NN 3000
#define NB 8
#define TP 12
#define DMAX 128
#define F1T 480    // block-1 packed features: h(8*24) + d(8*12) + w(8*24)
#define F2T 768    // block-2 packed features: 3 * 8 * 32

struct BrW {
    const float *W1[3]; const float *b1[3]; const float *c1w[3]; const float *c1b[3];
    const float *W2[3]; const float *b2[3]; const float *c2w[3]; const float *c2b[3];
    const float *Fb[3];
};

// ---------------- merged: Laplacian build (raw vals) + pack Xh|Xd|Xw -> xcat ----------------
__global__ void build_pack_kernel(const float* __restrict__ A, int* __restrict__ colp,
                                  float* __restrict__ valp, int* __restrict__ cnt,
                                  float* __restrict__ dinv,
                                  const float* __restrict__ Xh, const float* __restrict__ Xd,
                                  const float* __restrict__ Xw, float* __restrict__ xcat) {
    int bid = blockIdx.x;
    if (bid < 750) {
        int wid = threadIdx.x >> 6;
        int lane = threadIdx.x & 63;
        int n = bid * 4 + wid;            // 0..2999
        const float4* row4 = reinterpret_cast<const float4*>(A + (size_t)n * NN);
        int base = 0;
        float s = 0.f;
        for (int start = 0; start < 750; start += 64) {   // NN/4 = 750 float4s
            int m4 = start + lane;
            float4 v = make_float4(0.f, 0.f, 0.f, 0.f);
            if (m4 < 750) v = row4[m4];
            float vals[4] = {v.x, v.y, v.z, v.w};
            int mbase = m4 * 4;
            #pragma unroll
            for (int u = 0; u < 4; ++u) {
                int m = mbase + u;
                float a = (m4 < 750 && m != n) ? vals[u] : 0.f;
                bool nz = (a != 0.f);
                s += a;
                unsigned long long mask = __ballot(nz);
                int off = __popcll(mask & ((1ull << lane) - 1ull));
                if (nz) {
                    int idx = base + off;
                    if (idx < DMAX) { colp[n * DMAX + idx] = m; valp[n * DMAX + idx] = a; }
                }
                base += __popcll(mask);
            }
        }
        for (int o = 32; o > 0; o >>= 1) s += __shfl_down(s, o);
        if (lane == 0) {
            cnt[n] = (base < DMAX) ? base : DMAX;
            dinv[n] = (s > 0.f) ? 1.0f / sqrtf(s) : 0.f;
        }
    } else {
        int idx = (bid - 750) * 256 + threadIdx.x;
        if (idx >= NN * F1T) return;
        int n = idx / F1T, r = idx % F1T;
        const float* src; int b, t, T;
        if (r < 192)      { src = Xh; T = 24; int rr = r;       b = rr / 24; t = rr % 24; }
        else if (r < 288) { src = Xd; T = 12; int rr = r - 192; b = rr / 12; t = rr % 12; }
        else              { src = Xw; T = 24; int rr = r - 288; b = rr / 24; t = rr % 24; }
        xcat[idx] = src[((size_t)b * NN + n) * T + t];
    }
}

// ---------------- SpMM, scalar gathers, 32-deep ILP, XCD-swizzled slices ----------------
// Edge scaling -dinv[n]*a*dinv[m] folded into LDS staging (dinv is L1-hot, 12 KB).
// SLICE=128: per-slice footprint 1.5 MB, XCD spans <=2 slices = 3 MB < 4 MB L2.
// EPI 0: y = Lx ; EPI 1: y = 2*Lx - aux ; EPI 2: y = aux + 2*Lx
template <int F, int SLICE, int EPI>
__global__ void spmm_kernel(const int* __restrict__ colp, const float* __restrict__ valp,
                            const int* __restrict__ cnt, const float* __restrict__ dinv,
                            const float* __restrict__ x, const float* __restrict__ aux,
                            float* __restrict__ y) {
    int nwg = gridDim.x;
    int q = nwg >> 3;
    int bid = blockIdx.x;
    int w = (bid & 7) * q + (bid >> 3);   // XCD-contiguous chunks (nwg % 8 == 0)
    int slice = w / NN;
    int n = w - slice * NN;
    int f = slice * SLICE + threadIdx.x;

    __shared__ int   scol[DMAX];
    __shared__ float sval[DMAX];
    int c = cnt[n];
    float dn = -dinv[n];
    if (threadIdx.x < DMAX) {
        int j = threadIdx.x;
        bool ok = j < c;
        int m = ok ? colp[n * DMAX + j] : 0;
        scol[j] = ok ? m * F : 0;
        sval[j] = ok ? dn * valp[n * DMAX + j] * dinv[m] : 0.f;
    }
    __syncthreads();
    int c32 = (c + 31) & ~31;
    float a0 = 0.f, a1 = 0.f, a2 = 0.f, a3 = 0.f;
    float a4 = 0.f, a5 = 0.f, a6 = 0.f, a7 = 0.f;
    if (f < F) {
        for (int i = 0; i < c32; i += 32) {
            float g[32], w32[32];
            #pragma unroll
            for (int u = 0; u < 32; ++u) {
                int cc = scol[i + u];
                w32[u] = sval[i + u];
                g[u] = x[cc + f];
            }
            #pragma unroll
            for (int u = 0; u < 32; u += 8) {
                a0 += w32[u + 0] * g[u + 0]; a1 += w32[u + 1] * g[u + 1];
                a2 += w32[u + 2] * g[u + 2]; a3 += w32[u + 3] * g[u + 3];
                a4 += w32[u + 4] * g[u + 4]; a5 += w32[u + 5] * g[u + 5];
                a6 += w32[u + 6] * g[u + 6]; a7 += w32[u + 7] * g[u + 7];
            }
        }
    }
    if (f >= F) return;
    float acc = ((a0 + a1) + (a2 + a3)) + ((a4 + a5) + (a6 + a7));
    size_t o = (size_t)n * F + f;
    if (EPI == 1) acc = 2.f * acc - aux[o];
    else if (EPI == 2) acc = aux[o] + 2.f * acc;
    y[o] = acc;
}

// ---------------- fused block-1 combine (GEMM1+tconv) + y-GEMM (GEMM2) ----------------
// Round-12 structure (256 thr, 3 rows x 8/12 cols) + float4 z-reads over k.
#define SZ_LDA 68
template <int T, int OFF>
__device__ __forceinline__ void fused1_body(
        int tile, int br, const float* __restrict__ xcat, const float* __restrict__ t1cat,
        const float* __restrict__ t2cat, float* __restrict__ y1cat,
        float* __restrict__ y2cat, float* __restrict__ c0cat, const BrW& P, float* smem) {
    constexpr int K = 3 * T;
    constexpr int LDA = K + 4;           // multiple of 4 (float4 z-reads), banks OK
    int tid = threadIdx.x;
    float* sW1 = smem;                   // K*64
    float* sX  = smem + K * 64;          // 96*LDA
    const float* W1 = P.W1[br];
    for (int i = tid; i < K * 64; i += 256) sW1[i] = W1[i];
    int n0 = tile * 12;
    #pragma unroll
    for (int s = 0; s < 3; ++s) {
        const float* src = (s == 0) ? xcat : (s == 1) ? t1cat : t2cat;
        for (int i = tid; i < 96 * T; i += 256) {
            int n_l = i / (8 * T), rem = i % (8 * T);
            int b = rem / T, ii = rem % T;
            sX[(n_l * 8 + b) * LDA + s * T + ii] =
                src[(size_t)(n0 + n_l) * F1T + OFF + b * T + ii];
        }
    }
    __syncthreads();

    int rq = tid >> 3;       // 0..31 -> rows rq*3..rq*3+2
    int g  = tid & 7;        // cols g*8..g*8+7
    float acc[3][8];
    #pragma unroll
    for (int r = 0; r < 3; ++r)
        #pragma unroll
        for (int j = 0; j < 8; ++j) acc[r][j] = 0.f;

    for (int k4 = 0; k4 < K; k4 += 4) {
        float4 zq0 = *reinterpret_cast<const float4*>(sX + (rq * 3 + 0) * LDA + k4);
        float4 zq1 = *reinterpret_cast<const float4*>(sX + (rq * 3 + 1) * LDA + k4);
        float4 zq2 = *reinterpret_cast<const float4*>(sX + (rq * 3 + 2) * LDA + k4);
        #pragma unroll
        for (int kk = 0; kk < 4; ++kk) {
            const float4* wr = reinterpret_cast<const float4*>(sW1 + (k4 + kk) * 64 + g * 8);
            float4 wa = wr[0], wb = wr[1];
            float zv0 = (kk == 0) ? zq0.x : (kk == 1) ? zq0.y : (kk == 2) ? zq0.z : zq0.w;
            float zv1 = (kk == 0) ? zq1.x : (kk == 1) ? zq1.y : (kk == 2) ? zq1.z : zq1.w;
            float zv2 = (kk == 0) ? zq2.x : (kk == 1) ? zq2.y : (kk == 2) ? zq2.z : zq2.w;
            acc[0][0] += zv0 * wa.x; acc[0][1] += zv0 * wa.y;
            acc[0][2] += zv0 * wa.z; acc[0][3] += zv0 * wa.w;
            acc[0][4] += zv0 * wb.x; acc[0][5] += zv0 * wb.y;
            acc[0][6] += zv0 * wb.z; acc[0][7] += zv0 * wb.w;
            acc[1][0] += zv1 * wa.x; acc[1][1] += zv1 * wa.y;
            acc[1][2] += zv1 * wa.z; acc[1][3] += zv1 * wa.w;
            acc[1][4] += zv1 * wb.x; acc[1][5] += zv1 * wb.y;
            acc[1][6] += zv1 * wb.z; acc[1][7] += zv1 * wb.w;
            acc[2][0] += zv2 * wa.x; acc[2][1] += zv2 * wa.y;
            acc[2][2] += zv2 * wa.z; acc[2][3] += zv2 * wa.w;
            acc[2][4] += zv2 * wb.x; acc[2][5] += zv2 * wb.y;
            acc[2][6] += zv2 * wb.z; acc[2][7] += zv2 * wb.w;
        }
    }

    float bgv[8];
    #pragma unroll
    for (int j = 0; j < 8; ++j) bgv[j] = P.b1[br][g * 8 + j];
    float w0 = P.c1w[br][0], w1 = P.c1w[br][1], w2 = P.c1w[br][2], bb = P.c1b[br][0];

    float o[3][8];
    #pragma unroll
    for (int r = 0; r < 3; ++r) {
        float z[8];
        #pragma unroll
        for (int j = 0; j < 8; ++j) z[j] = fmaxf(acc[r][j] + bgv[j], 0.f);
        float zl = __shfl_up(z[7], 1);
        float zr = __shfl_down(z[0], 1);
        #pragma unroll
        for (int j = 0; j < 8; ++j) {
            float left  = (j > 0) ? z[j - 1] : ((g > 0) ? zl : 0.f);
            float right = (j < 7) ? z[j + 1] : ((g < 7) ? zr : 0.f);
            o[r][j] = fmaxf(w0 * left + w1 * z[j] + w2 * right + bb, 0.f);
        }
    }
    __syncthreads();   // all phase-1 LDS reads done; regions reused

    float* sZ  = smem;                 // 96 * SZ_LDA
    float* sW2 = smem + 96 * SZ_LDA;   // 64*96 interleaved
    #pragma unroll
    for (int r = 0; r < 3; ++r) {
        float* dst = sZ + (rq * 3 + r) * SZ_LDA + g * 8;
        reinterpret_cast<float4*>(dst)[0] = make_float4(o[r][0], o[r][1], o[r][2], o[r][3]);
        reinterpret_cast<float4*>(dst)[1] = make_float4(o[r][4], o[r][5], o[r][6], o[r][7]);
    }
    const float* W2 = P.W2[br];        // (3, 64, 32)
    for (int i = tid; i < 6144; i += 256) {
        int k = i / 96, cc = i % 96;
        int j = cc / 3, m = cc % 3;
        sW2[i] = W2[m * 2048 + k * 32 + j];
    }
    __syncthreads();

    float acc2[3][12];
    #pragma unroll
    for (int r = 0; r < 3; ++r)
        #pragma unroll
        for (int j = 0; j < 12; ++j) acc2[r][j] = 0.f;

    for (int k4 = 0; k4 < 64; k4 += 4) {
        float4 zq0 = *reinterpret_cast<const float4*>(sZ + (rq * 3 + 0) * SZ_LDA + k4);
        float4 zq1 = *reinterpret_cast<const float4*>(sZ + (rq * 3 + 1) * SZ_LDA + k4);
        float4 zq2 = *reinterpret_cast<const float4*>(sZ + (rq * 3 + 2) * SZ_LDA + k4);
        #pragma unroll
        for (int kk = 0; kk < 4; ++kk) {
            const float4* wr = reinterpret_cast<const float4*>(sW2 + (k4 + kk) * 96 + g * 12);
            float4 wa = wr[0], wb = wr[1], wc = wr[2];
            float zv0 = (kk == 0) ? zq0.x : (kk == 1) ? zq0.y : (kk == 2) ? zq0.z : zq0.w;
            float zv1 = (kk == 0) ? zq1.x : (kk == 1) ? zq1.y : (kk == 2) ? zq1.z : zq1.w;
            float zv2 = (kk == 0) ? zq2.x : (kk == 1) ? zq2.y : (kk == 2) ? zq2.z : zq2.w;
            acc2[0][0] += zv0 * wa.x;  acc2[0][1] += zv0 * wa.y;
            acc2[0][2] += zv0 * wa.z;  acc2[0][3] += zv0 * wa.w;
            acc2[0][4] += zv0 * wb.x;  acc2[0][5] += zv0 * wb.y;
            acc2[0][6] += zv0 * wb.z;  acc2[0][7] += zv0 * wb.w;
            acc2[0][8] += zv0 * wc.x;  acc2[0][9] += zv0 * wc.y;
            acc2[0][10] += zv0 * wc.z; acc2[0][11] += zv0 * wc.w;
            acc2[1][0] += zv1 * wa.x;  acc2[1][1] += zv1 * wa.y;
            acc2[1][2] += zv1 * wa.z;  acc2[1][3] += zv1 * wa.w;
            acc2[1][4] += zv1 * wb.x;  acc2[1][5] += zv1 * wb.y;
            acc2[1][6] += zv1 * wb.z;  acc2[1][7] += zv1 * wb.w;
            acc2[1][8] += zv1 * wc.x;  acc2[1][9] += zv1 * wc.y;
            acc2[1][10] += zv1 * wc.z; acc2[1][11] += zv1 * wc.w;
            acc2[2][0] += zv2 * wa.x;  acc2[2][1] += zv2 * wa.y;
            acc2[2][2] += zv2 * wa.z;  acc2[2][3] += zv2 * wa.w;
            acc2[2][4] += zv2 * wb.x;  acc2[2][5] += zv2 * wb.y;
            acc2[2][6] += zv2 * wb.z;  acc2[2][7] += zv2 * wb.w;
            acc2[2][8] += zv2 * wc.x;  acc2[2][9] += zv2 * wc.y;
            acc2[2][10] += zv2 * wc.z; acc2[2][11] += zv2 * wc.w;
        }
    }

    const float* b2 = P.b2[br];
    #pragma unroll
    for (int r = 0; r < 3; ++r) {
        int unit = tile * 96 + rq * 3 + r;
        int n = unit >> 3, b = unit & 7;
        size_t obase = (size_t)n * F2T + br * 256 + b * 32;
        #pragma unroll
        for (int jj = 0; jj < 4; ++jj) {
            int j = g * 4 + jj;
            float a0 = acc2[r][jj * 3 + 0], a1 = acc2[r][jj * 3 + 1], a2 = acc2[r][jj * 3 + 2];
            y1cat[obase + j] = a1;
            y2cat[obase + j] = a2;
            c0cat[obase + j] = a0 - a2 + b2[j];
        }
    }
}

__global__ void __launch_bounds__(256, 2)
fused1_kernel(const float* __restrict__ xcat, const float* __restrict__ t1cat,
              const float* __restrict__ t2cat, float* __restrict__ y1cat,
              float* __restrict__ y2cat, float* __restrict__ c0cat, BrW P) {
    __shared__ float smem[12672];   // 50.7 KB union: max(K*64+96*(K+4), 96*68+6144)
    int b = blockIdx.x;
    if (b < 250)      fused1_body<24, 0>(b, 0, xcat, t1cat, t2cat, y1cat, y2cat, c0cat, P, smem);
    else if (b < 500) fused1_body<12, 192>(b - 250, 1, xcat, t1cat, t2cat, y1cat, y2cat, c0cat, P, smem);
    else              fused1_body<24, 288>(b - 500, 2, xcat, t1cat, t2cat, y1cat, y2cat, c0cat, P, smem);
}

// ---------------- block-2 combine + final linear + fusion, per node ----------------
__global__ void combine2_final_kernel(const float* __restrict__ c0cat,
                                      const float* __restrict__ vcat,
                                      const float* __restrict__ WD, const float* __restrict__ bD,
                                      float* __restrict__ out, BrW P) {
    int n = blockIdx.x;
    __shared__ float z2[3][NB][32];
    int unit = threadIdx.x >> 5;      // 0..23
    int co = threadIdx.x & 31;
    int br = unit >> 3, b = unit & 7;
    size_t o = (size_t)n * F2T + br * 256 + b * 32 + co;
    float a = fmaxf(c0cat[o] + vcat[o], 0.f);
    float left  = __shfl_up(a, 1);
    float right = __shfl_down(a, 1);
    if (co == 0) left = 0.f;
    if (co == 31) right = 0.f;
    float w0 = P.c2w[br][0], w1 = P.c2w[br][1], w2 = P.c2w[br][2], bb = P.c2b[br][0];
    z2[br][b][co] = fmaxf(w0 * left + w1 * a + w2 * right + bb, 0.f);
    __syncthreads();
    if (threadIdx.x < NB * TP) {
        int b2 = threadIdx.x / TP, tp = threadIdx.x % TP;
        float y = 0.f;
        for (int brr = 0; brr < 3; ++brr) {
            float s = bD[tp];
            const float* zz = z2[brr][b2];
            for (int c = 0; c < 32; ++c) s += zz[c] * WD[c * TP + tp];
            y += fmaxf(s, 0.f) * P.Fb[brr][tp];
        }
        out[((size_t)b2 * NN + n) * TP + tp] = y;
    }
}

// ---------------- launcher ----------------

static inline size_t align256(size_t x) { return (x + 255) & ~(size_t)255; }

extern "C" void kernel_launch(void* const* d_in, const int* in_sizes, int n_in,
                              void* d_out, int out_size, void* d_ws, size_t ws_size,
                              hipStream_t stream) {
    const float* Xh = (const float*)d_in[0];
    const float* Xd = (const float*)d_in[1];
    const float* Xw = (const float*)d_in[2];
    const float* A  = (const float*)d_in[3];
    const float* WD = (const float*)d_in[28];
    const float* bD = (const float*)d_in[29];

    BrW P;
    for (int br = 0; br < 3; ++br) {
        int base = 4 + br * 8;
        P.W1[br]  = (const float*)d_in[base + 0];
        P.b1[br]  = (const float*)d_in[base + 1];
        P.c1w[br] = (const float*)d_in[base + 2];
        P.c1b[br] = (const float*)d_in[base + 3];
        P.W2[br]  = (const float*)d_in[base + 4];
        P.b2[br]  = (const float*)d_in[base + 5];
        P.c2w[br] = (const float*)d_in[base + 6];
        P.c2b[br] = (const float*)d_in[base + 7];
        P.Fb[br]  = (const float*)d_in[30 + br];
    }

    char* p = (char*)d_ws;
    int*   colp  = (int*)p;   p += align256((size_t)NN * DMAX * 4);
    float* valp  = (float*)p; p += align256((size_t)NN * DMAX * 4);
    int*   cnt   = (int*)p;   p += align256(NN * 4);
    float* dinv  = (float*)p; p += align256(NN * 4);
    float* xcat  = (float*)p; p += align256((size_t)NN * F1T * 4);
    float* t1cat = (float*)p; p += align256((size_t)NN * F1T * 4);
    float* t2cat = (float*)p; p += align256((size_t)NN * F1T * 4);
    float* y1cat = (float*)p; p += align256((size_t)NN * F2T * 4);
    float* y2cat = (float*)p; p += align256((size_t)NN * F2T * 4);
    float* c0cat = (float*)p; p += align256((size_t)NN * F2T * 4);
    float* scat  = (float*)p; p += align256((size_t)NN * F2T * 4);
    float* vcat  = (float*)p; p += align256((size_t)NN * F2T * 4);

    // build (750 blocks, 4 rows each) + pack (5625 blocks), overlapped in one launch
    build_pack_kernel<<<750 + 5625, 256, 0, stream>>>(A, colp, valp, cnt, dinv,
                                                      Xh, Xd, Xw, xcat);

    // Block 1 (packed, F=480, 4 slices of 128): t1 = L x ; t2 = 2 L t1 - x
    spmm_kernel<F1T, 128, 0><<<12000, 128, 0, stream>>>(colp, valp, cnt, dinv, xcat, nullptr, t1cat);
    spmm_kernel<F1T, 128, 1><<<12000, 128, 0, stream>>>(colp, valp, cnt, dinv, t1cat, xcat, t2cat);

    // Fused: combine1 (cheb+bias+relu+tconv+relu) + W-first y-GEMM
    fused1_kernel<<<750, 256, 0, stream>>>(xcat, t1cat, t2cat, y1cat, y2cat, c0cat, P);

    // Block 2 (6 slices of 128): s = y1 + 2 L y2 ; v = L s ; then combine2 + final + fusion
    spmm_kernel<F2T, 128, 2><<<18000, 128, 0, stream>>>(colp, valp, cnt, dinv, y2cat, y1cat, scat);
    spmm_kernel<F2T, 128, 0><<<18000, 128, 0, stream>>>(colp, valp, cnt, dinv, scat, nullptr, vcat);

    combine2_final_kernel<<<NN, 768, 0, stream>>>(c0cat, vcat, WD, bD, (float*)d_out, P);
}